// Round 9
// baseline (739.238 us; speedup 1.0000x reference)
//
#include <hip/hip_runtime.h>
#include <cstdint>
#include <cstddef>

#define LOG2E 1.442695040888963f

__device__ __forceinline__ float rdlane(float v, int lane) {
    return __int_as_float(__builtin_amdgcn_readlane(__float_as_int(v), lane));
}

template <int Q>
__device__ __forceinline__ float quad_bcast(float v) {
    // quad_perm broadcast of lane Q within each quad of 4 lanes
    return __int_as_float(__builtin_amdgcn_update_dpp(
        0, __float_as_int(v), Q * 0x55, 0xF, 0xF, true));
}

// proj[d][v][s] = m(s) * (b[row] + W_ih[row,:] . emb[v,:]),  s = 4*j+g, row = g*15+j.
__global__ __launch_bounds__(256) void proj_kernel(
    const float* __restrict__ emb,
    const float* __restrict__ w_ih_f, const float* __restrict__ b_f,
    const float* __restrict__ w_ih_b, const float* __restrict__ b_b,
    float* __restrict__ proj, int V) {
    int gid = blockIdx.x * 256 + threadIdx.x;
    if (gid >= 2 * V * 64) return;
    int s = gid & 63;
    int v = (gid >> 6) % V;
    int d = gid / (V * 64);
    if (s >= 60) { proj[gid] = 0.0f; return; }
    int j = s >> 2, g = s & 3;
    int row = g * 15 + j;
    const float* w  = d ? w_ih_b : w_ih_f;
    const float* bv = d ? b_b   : b_f;
    float m = (g == 2) ? (-2.0f * LOG2E) : (-LOG2E);
    float acc = bv[row];
    #pragma unroll
    for (int k = 0; k < 15; ++k)
        acc = fmaf(emb[v * 15 + k], w[row * 15 + k], acc);
    proj[gid] = m * acc;
}

// One wave per (direction, sample). Lane = 4*j + g (g: 0=i 1=f 2=g 3=o). R7-exact.
__global__ __launch_bounds__(64) void lstm_kernel(
    const int* __restrict__ data, const int* __restrict__ lengths,
    const float* __restrict__ proj,
    const float* __restrict__ h0, const float* __restrict__ c0,
    const float* __restrict__ w_hh_f, const float* __restrict__ w_hh_b,
    float* __restrict__ out, int T, int V) {
    const int lane = threadIdx.x;
    const int dir = blockIdx.x >> 6;
    const int b = blockIdx.x & 63;
    const int L = lengths[b];

    if (lane >= 60) return;

    const int j = lane >> 2;
    const int g = lane & 3;
    const int row = g * 15 + j;
    const float K = -2.0f * LOG2E;

    const float* whh = dir ? w_hh_b : w_hh_f;
    const float mm = (g == 2) ? K : (-LOG2E);

    const bool gm0 = (g == 0), gm1 = (g == 1), gm2 = (g == 2), gm3 = (g == 3);

    float wh[15];
    #pragma unroll
    for (int k = 0; k < 15; ++k) wh[k] = whh[row * 15 + k] * mm;

    float h = h0[(dir * 64 + b) * 15 + j];        // replicated across quad
    float C = K * c0[(dir * 64 + b) * 15 + j];    // pre-scaled cell state

    const int* drow = data + (size_t)b * T;
    const float* pj = proj + (size_t)dir * V * 64 + lane;
    const int sgn  = dir ? -1 : 1;
    const int base = dir ? (L - 1) : 0;

    float* wp = out + ((size_t)b * T + (size_t)(dir ? (L - 1 - g) : g)) * 45 + dir * 15 + j;
    float* outp = out + ((size_t)b * T) * 45 + dir * 15 + j;

    auto tok = [&](int t) -> int {
        int tt = t < L ? t : L - 1;
        return drow[base + sgn * tt];
    };

    auto step = [&](float xg) {
        float hk0 = rdlane(h, 0),  hk1 = rdlane(h, 4),  hk2 = rdlane(h, 8);
        float hk3 = rdlane(h, 12), hk4 = rdlane(h, 16), hk5 = rdlane(h, 20);
        float hk6 = rdlane(h, 24), hk7 = rdlane(h, 28), hk8 = rdlane(h, 32);
        float hk9 = rdlane(h, 36), hk10 = rdlane(h, 40), hk11 = rdlane(h, 44);
        float hk12 = rdlane(h, 48), hk13 = rdlane(h, 52), hk14 = rdlane(h, 56);
        float a0 = xg, a1 = 0.f, a2 = 0.f, a3 = 0.f;
        a0 = fmaf(hk0,  wh[0],  a0);  a1 = fmaf(hk1,  wh[1],  a1);
        a2 = fmaf(hk2,  wh[2],  a2);  a3 = fmaf(hk3,  wh[3],  a3);
        a0 = fmaf(hk4,  wh[4],  a0);  a1 = fmaf(hk5,  wh[5],  a1);
        a2 = fmaf(hk6,  wh[6],  a2);  a3 = fmaf(hk7,  wh[7],  a3);
        a0 = fmaf(hk8,  wh[8],  a0);  a1 = fmaf(hk9,  wh[9],  a1);
        a2 = fmaf(hk10, wh[10], a2);  a3 = fmaf(hk11, wh[11], a3);
        a0 = fmaf(hk12, wh[12], a0);  a1 = fmaf(hk13, wh[13], a1);
        float s = (a0 + a1) + (a2 + a3);
        float z = fmaf(hk14, wh[14], s);
        float w = __builtin_amdgcn_rcpf(1.0f + __builtin_amdgcn_exp2f(z));
        float wf = quad_bcast<1>(w);          // f first: on the C critical path
        float wi = quad_bcast<0>(w);
        float wg = quad_bcast<2>(w);
        float wo = quad_bcast<3>(w);
        float tg = fmaf(2.0f, wg, -1.0f);     // tanh(z_g)
        float ai = K * wi;
        C = fmaf(wf, C, ai * tg);             // C = -2log2e * c
        float wc = __builtin_amdgcn_rcpf(1.0f + __builtin_amdgcn_exp2f(C));
        float p2 = wo + wo;
        h = fmaf(p2, wc, -wo);                // vo * tanh(c), replicated in quad
    };

    float xA[8], xB[8];
    int ta[8], tb[8];

    #pragma unroll
    for (int u = 0; u < 8; ++u) ta[u] = tok(u);
    #pragma unroll
    for (int u = 0; u < 8; ++u) xA[u] = pj[(size_t)ta[u] * 64];
    #pragma unroll
    for (int u = 0; u < 8; ++u) ta[u] = tok(8 + u);
    #pragma unroll
    for (int u = 0; u < 8; ++u) xB[u] = pj[(size_t)ta[u] * 64];
    #pragma unroll
    for (int u = 0; u < 8; ++u) ta[u] = tok(16 + u);
    #pragma unroll
    for (int u = 0; u < 8; ++u) tb[u] = tok(24 + u);

    auto halfrun = [&](float (&xb)[8], int (&tkb)[8], int th) {
        float hc = h;
        step(xb[0]); hc = gm0 ? h : hc;
        step(xb[1]); hc = gm1 ? h : hc;
        step(xb[2]); hc = gm2 ? h : hc;
        step(xb[3]); hc = gm3 ? h : hc;
        __builtin_nontemporal_store(hc, wp + (ptrdiff_t)sgn * th * 45);
        step(xb[4]); hc = gm0 ? h : hc;
        step(xb[5]); hc = gm1 ? h : hc;
        step(xb[6]); hc = gm2 ? h : hc;
        step(xb[7]); hc = gm3 ? h : hc;
        __builtin_nontemporal_store(hc, wp + (ptrdiff_t)sgn * (th + 4) * 45);
        #pragma unroll
        for (int u = 0; u < 8; ++u) xb[u] = pj[(size_t)tkb[u] * 64];
        #pragma unroll
        for (int u = 0; u < 8; ++u) tkb[u] = tok(th + 32 + u);
    };

    int t = 0;
    for (; t + 16 <= L; t += 16) {
        halfrun(xA, ta, t);
        halfrun(xB, tb, t + 8);
    }
    #pragma unroll 1
    for (int u = 0; u < 8 && t < L; ++u, ++t) {
        step(xA[u]);
        outp[(size_t)(base + sgn * t) * 45] = h;
    }
    #pragma unroll 1
    for (int u = 0; u < 8 && t < L; ++u, ++t) {
        step(xB[u]);
        outp[(size_t)(base + sgn * t) * 45] = h;
    }
}

// LDS-tiled epilogue: block = 128 consecutive rows of one batch.
// Stage X (cols 0..29) coalesced -> LDS, compute, stage Y -> LDS, write the
// 128x45 output tile as ONE contiguous coalesced range (base + r*45 + c).
__global__ __launch_bounds__(256) void linear_kernel(
    const int* __restrict__ lengths,
    const float* __restrict__ lin_w, const float* __restrict__ lin_b,
    float* __restrict__ out, int T) {
    __shared__ float Ws[45 * 30];
    __shared__ float Bs[45];
    __shared__ float Xs[128 * 30];
    __shared__ float Ys[128 * 45];
    const int tid = threadIdx.x;
    const int b = blockIdx.y;
    const int t0 = blockIdx.x * 128;
    const int nrow = min(128, T - t0);

    for (int i = tid; i < 45 * 30; i += 256) Ws[i] = lin_w[i];
    if (tid < 45) Bs[tid] = lin_b[tid];
    const int L = lengths[b];
    float* base = out + ((size_t)b * T + t0) * 45;

    // stage input cols 0..29 of each row (mostly-contiguous 120B runs)
    for (int i = tid; i < nrow * 30; i += 256) {
        int r = i / 30, k = i - 30 * r;
        Xs[i] = base[r * 45 + k];
    }
    __syncthreads();

    for (int i = tid; i < nrow * 45; i += 256) {
        int r = i / 45, c = i - 45 * r;
        float acc = Bs[c];
        if (t0 + r < L) {
            const float* xr = Xs + r * 30;
            const float* wr = Ws + c * 30;
            #pragma unroll
            for (int k = 0; k < 30; ++k) acc = fmaf(xr[k], wr[k], acc);
        }
        Ys[i] = acc;
    }
    __syncthreads();

    // one fully-coalesced contiguous write of the whole tile
    for (int i = tid; i < nrow * 45; i += 256) base[i] = Ys[i];
}

extern "C" void kernel_launch(void* const* d_in, const int* in_sizes, int n_in,
                              void* d_out, int out_size, void* d_ws, size_t ws_size,
                              hipStream_t stream) {
    const int* data      = (const int*)d_in[0];
    const int* lengths   = (const int*)d_in[2];
    const float* emb     = (const float*)d_in[3];
    const float* h0      = (const float*)d_in[4];
    const float* c0      = (const float*)d_in[5];
    const float* w_ih_f  = (const float*)d_in[6];
    const float* w_hh_f  = (const float*)d_in[7];
    const float* b_f     = (const float*)d_in[8];
    const float* w_ih_b  = (const float*)d_in[9];
    const float* w_hh_b  = (const float*)d_in[10];
    const float* b_b     = (const float*)d_in[11];
    const float* lin_w   = (const float*)d_in[12];
    const float* lin_b   = (const float*)d_in[13];
    float* out = (float*)d_out;

    const int T = in_sizes[0] / 64;
    const int V = in_sizes[3] / 15;
    float* proj = (float*)d_ws;   // 2*V*64 floats = 25.6 MB

    hipLaunchKernelGGL(proj_kernel, dim3((2 * V * 64 + 255) / 256), dim3(256), 0, stream,
                       emb, w_ih_f, b_f, w_ih_b, b_b, proj, V);
    hipLaunchKernelGGL(lstm_kernel, dim3(128), dim3(64), 0, stream,
                       data, lengths, proj, h0, c0, w_hh_f, w_hh_b, out, T, V);
    hipLaunchKernelGGL(linear_kernel, dim3((T + 127) / 128, 64), dim3(256), 0, stream,
                       lengths, lin_w, lin_b, out, T);
}

// Round 10
// 661.399 us; speedup vs baseline: 1.1177x; 1.1177x over previous
//
#include <hip/hip_runtime.h>
#include <cstdint>
#include <cstddef>

#define LOG2E 1.442695040888963f

__device__ __forceinline__ float rdlane(float v, int lane) {
    return __int_as_float(__builtin_amdgcn_readlane(__float_as_int(v), lane));
}

template <int Q>
__device__ __forceinline__ float quad_bcast(float v) {
    // quad_perm broadcast of lane Q within each quad of 4 lanes
    return __int_as_float(__builtin_amdgcn_update_dpp(
        0, __float_as_int(v), Q * 0x55, 0xF, 0xF, true));
}

// proj[d][v][4j+g] = m(g) * (b[g*15+j] + W_ih[g*15+j,:] . emb[v,:])
// One thread per (d, v, j): computes all 4 gates, stores one aligned float4.
// (Slots 60..63 of each 64-float row are never read by lstm_kernel.)
__global__ __launch_bounds__(256) void proj_kernel(
    const float* __restrict__ emb,
    const float* __restrict__ w_ih_f, const float* __restrict__ b_f,
    const float* __restrict__ w_ih_b, const float* __restrict__ b_b,
    float* __restrict__ proj, int V) {
    int gid = blockIdx.x * 256 + threadIdx.x;
    int j = gid & 15;
    int rowid = gid >> 4;            // d*V + v
    if (j >= 15 || rowid >= 2 * V) return;
    int v = rowid % V;
    int d = rowid / V;
    const float* w  = d ? w_ih_b : w_ih_f;
    const float* bv = d ? b_b   : b_f;

    float x[15];
    #pragma unroll
    for (int k = 0; k < 15; ++k) x[k] = emb[v * 15 + k];

    float4 r;
    float* rp = &r.x;
    #pragma unroll
    for (int g = 0; g < 4; ++g) {
        int row = g * 15 + j;
        float acc = bv[row];
        #pragma unroll
        for (int k = 0; k < 15; ++k) acc = fmaf(x[k], w[row * 15 + k], acc);
        rp[g] = ((g == 2) ? (-2.0f * LOG2E) : (-LOG2E)) * acc;
    }
    *(float4*)(proj + (size_t)rowid * 64 + 4 * j) = r;
}

// One wave per (direction, sample). Lane = 4*j + g (g: 0=i 1=f 2=g 3=o). R7-proven
// structure; single micro-fold: K*sigma(zi)*tanh(zg) = wi * fma(2K, wg, -K).
__global__ __launch_bounds__(64) void lstm_kernel(
    const int* __restrict__ data, const int* __restrict__ lengths,
    const float* __restrict__ proj,
    const float* __restrict__ h0, const float* __restrict__ c0,
    const float* __restrict__ w_hh_f, const float* __restrict__ w_hh_b,
    float* __restrict__ out, int T, int V) {
    const int lane = threadIdx.x;
    const int dir = blockIdx.x >> 6;
    const int b = blockIdx.x & 63;
    const int L = lengths[b];

    if (lane >= 60) return;

    const int j = lane >> 2;
    const int g = lane & 3;
    const int row = g * 15 + j;
    const float K = -2.0f * LOG2E;

    const float* whh = dir ? w_hh_b : w_hh_f;
    const float mm = (g == 2) ? K : (-LOG2E);

    const bool gm0 = (g == 0), gm1 = (g == 1), gm2 = (g == 2), gm3 = (g == 3);

    float wh[15];
    #pragma unroll
    for (int k = 0; k < 15; ++k) wh[k] = whh[row * 15 + k] * mm;

    float h = h0[(dir * 64 + b) * 15 + j];        // replicated across quad
    float C = K * c0[(dir * 64 + b) * 15 + j];    // pre-scaled cell state

    const int* drow = data + (size_t)b * T;
    const float* pj = proj + (size_t)dir * V * 64 + lane;
    const int sgn  = dir ? -1 : 1;
    const int base = dir ? (L - 1) : 0;

    float* wp = out + ((size_t)b * T + (size_t)(dir ? (L - 1 - g) : g)) * 45 + dir * 15 + j;
    float* outp = out + ((size_t)b * T) * 45 + dir * 15 + j;

    auto tok = [&](int t) -> int {
        int tt = t < L ? t : L - 1;
        return drow[base + sgn * tt];
    };

    auto step = [&](float xg) {
        float hk0 = rdlane(h, 0),  hk1 = rdlane(h, 4),  hk2 = rdlane(h, 8);
        float hk3 = rdlane(h, 12), hk4 = rdlane(h, 16), hk5 = rdlane(h, 20);
        float hk6 = rdlane(h, 24), hk7 = rdlane(h, 28), hk8 = rdlane(h, 32);
        float hk9 = rdlane(h, 36), hk10 = rdlane(h, 40), hk11 = rdlane(h, 44);
        float hk12 = rdlane(h, 48), hk13 = rdlane(h, 52), hk14 = rdlane(h, 56);
        float a0 = xg, a1 = 0.f, a2 = 0.f, a3 = 0.f;
        a0 = fmaf(hk0,  wh[0],  a0);  a1 = fmaf(hk1,  wh[1],  a1);
        a2 = fmaf(hk2,  wh[2],  a2);  a3 = fmaf(hk3,  wh[3],  a3);
        a0 = fmaf(hk4,  wh[4],  a0);  a1 = fmaf(hk5,  wh[5],  a1);
        a2 = fmaf(hk6,  wh[6],  a2);  a3 = fmaf(hk7,  wh[7],  a3);
        a0 = fmaf(hk8,  wh[8],  a0);  a1 = fmaf(hk9,  wh[9],  a1);
        a2 = fmaf(hk10, wh[10], a2);  a3 = fmaf(hk11, wh[11], a3);
        a0 = fmaf(hk12, wh[12], a0);  a1 = fmaf(hk13, wh[13], a1);
        float s = (a0 + a1) + (a2 + a3);
        float z = fmaf(hk14, wh[14], s);
        float w = __builtin_amdgcn_rcpf(1.0f + __builtin_amdgcn_exp2f(z));
        float wf = quad_bcast<1>(w);          // f first: on the C critical path
        float wi = quad_bcast<0>(w);
        float wg = quad_bcast<2>(w);
        float wo = quad_bcast<3>(w);
        float tg2 = fmaf(2.0f * K, wg, -K);   // K * tanh(z_g)
        C = fmaf(wf, C, wi * tg2);            // C = -2log2e * c
        float wc = __builtin_amdgcn_rcpf(1.0f + __builtin_amdgcn_exp2f(C));
        float p2 = wo + wo;
        h = fmaf(p2, wc, -wo);                // vo * tanh(c), replicated in quad
    };

    float xA[8], xB[8];
    int ta[8], tb[8];

    #pragma unroll
    for (int u = 0; u < 8; ++u) ta[u] = tok(u);
    #pragma unroll
    for (int u = 0; u < 8; ++u) xA[u] = pj[(size_t)ta[u] * 64];
    #pragma unroll
    for (int u = 0; u < 8; ++u) ta[u] = tok(8 + u);
    #pragma unroll
    for (int u = 0; u < 8; ++u) xB[u] = pj[(size_t)ta[u] * 64];
    #pragma unroll
    for (int u = 0; u < 8; ++u) ta[u] = tok(16 + u);
    #pragma unroll
    for (int u = 0; u < 8; ++u) tb[u] = tok(24 + u);

    auto halfrun = [&](float (&xb)[8], int (&tkb)[8], int th) {
        float hc = h;
        step(xb[0]); hc = gm0 ? h : hc;
        step(xb[1]); hc = gm1 ? h : hc;
        step(xb[2]); hc = gm2 ? h : hc;
        step(xb[3]); hc = gm3 ? h : hc;
        __builtin_nontemporal_store(hc, wp + (ptrdiff_t)sgn * th * 45);
        step(xb[4]); hc = gm0 ? h : hc;
        step(xb[5]); hc = gm1 ? h : hc;
        step(xb[6]); hc = gm2 ? h : hc;
        step(xb[7]); hc = gm3 ? h : hc;
        __builtin_nontemporal_store(hc, wp + (ptrdiff_t)sgn * (th + 4) * 45);
        #pragma unroll
        for (int u = 0; u < 8; ++u) xb[u] = pj[(size_t)tkb[u] * 64];
        #pragma unroll
        for (int u = 0; u < 8; ++u) tkb[u] = tok(th + 32 + u);
    };

    int t = 0;
    for (; t + 16 <= L; t += 16) {
        halfrun(xA, ta, t);
        halfrun(xB, tb, t + 8);
    }
    #pragma unroll 1
    for (int u = 0; u < 8 && t < L; ++u, ++t) {
        step(xA[u]);
        outp[(size_t)(base + sgn * t) * 45] = h;
    }
    #pragma unroll 1
    for (int u = 0; u < 8 && t < L; ++u, ++t) {
        step(xB[u]);
        outp[(size_t)(base + sgn * t) * 45] = h;
    }
}

// Epilogue (R7/R8-proven): in-place linear 30 -> 45 per (b,t) row; t >= L rows get lin_b.
__global__ __launch_bounds__(256) void linear_kernel(
    const int* __restrict__ lengths,
    const float* __restrict__ lin_w, const float* __restrict__ lin_b,
    float* out, int T) {
    __shared__ float Ws[45 * 30];
    __shared__ float Bs[45];
    for (int i = threadIdx.x; i < 45 * 30; i += 256) Ws[i] = lin_w[i];
    if (threadIdx.x < 45) Bs[threadIdx.x] = lin_b[threadIdx.x];
    __syncthreads();
    const int b = blockIdx.y;
    const int t = blockIdx.x * 256 + threadIdx.x;
    if (t >= T) return;
    const int L = lengths[b];
    float* row = out + ((size_t)b * T + t) * 45;
    float y[45];
    if (t < L) {
        float x[30];
        #pragma unroll
        for (int k = 0; k < 30; ++k) x[k] = row[k];
        #pragma unroll
        for (int o = 0; o < 45; ++o) {
            float acc = Bs[o];
            #pragma unroll
            for (int k = 0; k < 30; ++k) acc = fmaf(x[k], Ws[o * 30 + k], acc);
            y[o] = acc;
        }
    } else {
        #pragma unroll
        for (int o = 0; o < 45; ++o) y[o] = Bs[o];
    }
    #pragma unroll
    for (int o = 0; o < 45; ++o) row[o] = y[o];
}

extern "C" void kernel_launch(void* const* d_in, const int* in_sizes, int n_in,
                              void* d_out, int out_size, void* d_ws, size_t ws_size,
                              hipStream_t stream) {
    const int* data      = (const int*)d_in[0];
    const int* lengths   = (const int*)d_in[2];
    const float* emb     = (const float*)d_in[3];
    const float* h0      = (const float*)d_in[4];
    const float* c0      = (const float*)d_in[5];
    const float* w_ih_f  = (const float*)d_in[6];
    const float* w_hh_f  = (const float*)d_in[7];
    const float* b_f     = (const float*)d_in[8];
    const float* w_ih_b  = (const float*)d_in[9];
    const float* w_hh_b  = (const float*)d_in[10];
    const float* b_b     = (const float*)d_in[11];
    const float* lin_w   = (const float*)d_in[12];
    const float* lin_b   = (const float*)d_in[13];
    float* out = (float*)d_out;

    const int T = in_sizes[0] / 64;
    const int V = in_sizes[3] / 15;
    float* proj = (float*)d_ws;   // 2*V*64 floats = 25.6 MB

    hipLaunchKernelGGL(proj_kernel, dim3((2 * V * 16 + 255) / 256), dim3(256), 0, stream,
                       emb, w_ih_f, b_f, w_ih_b, b_b, proj, V);
    hipLaunchKernelGGL(lstm_kernel, dim3(128), dim3(64), 0, stream,
                       data, lengths, proj, h0, c0, w_hh_f, w_hh_b, out, T, V);
    hipLaunchKernelGGL(linear_kernel, dim3((T + 255) / 256, 64), dim3(256), 0, stream,
                       lengths, lin_w, lin_b, out, T);
}